// Round 4
// baseline (757.698 us; speedup 1.0000x reference)
//
#include <hip/hip_runtime.h>
#include <hip/hip_bf16.h>
#include <stdint.h>

// BinaryTreeLSTM on MI355X (gfx950) — round 4: single persistent kernel.
//  - 256 blocks x 512 thr; 120KB LDS forces exactly 1 block/CU -> all blocks
//    co-resident (grid == #CU), 8 waves/CU = 2/SIMD for latency hiding.
//  - Each block owns j-tile jt (32 cols x 5 gates), packs its weight slice
//    fp32->bf16 into LDS ONCE, then processes all 10 levels; manual
//    device-scope grid barrier between levels; classifier fused at the end.
//  - K-loop: A-frags global->VGPR (depth-1 prefetch), B from LDS, 10
//    independent 32x32x16 bf16 MFMAs per k-step, zero barriers.
//  - jt=(blk>>3)&3, stripe=(blk&7)+8*(blk>>5): 4 jt-replicas of a stripe land
//    on the same XCD -> A rows served by that XCD's L2 after one HBM fetch.

#define BATCH 256
#define TDEPTH 10
#define NTOT 1023
#define HDIM 128
#define NCLS 5
#define GDIM 384
#define NKS 24          // k-steps of 16 across GDIM
#define NBLK 256

typedef __bf16 bf16x8 __attribute__((ext_vector_type(8)));
typedef float f32x16 __attribute__((ext_vector_type(16)));

__device__ __forceinline__ float sigmoid_f(float v) { return 1.f / (1.f + __expf(-v)); }
__device__ __forceinline__ float tanh_f(float v) { return 1.f - 2.f / (1.f + __expf(2.f * v)); }

__device__ __forceinline__ void gbar(unsigned* ctr, unsigned target) {
  __syncthreads();
  if (threadIdx.x == 0) {
    __threadfence();  // release our h/c writes to device scope
    __hip_atomic_fetch_add(ctr, 1u, __ATOMIC_RELAXED, __HIP_MEMORY_SCOPE_AGENT);
    while (__hip_atomic_load(ctr, __ATOMIC_RELAXED, __HIP_MEMORY_SCOPE_AGENT) < target)
      __builtin_amdgcn_s_sleep(1);
    (void)__hip_atomic_load(ctr, __ATOMIC_ACQUIRE, __HIP_MEMORY_SCOPE_AGENT);  // L1 inval
  }
  __syncthreads();
}

__global__ __launch_bounds__(512, 2) void fused_kernel(
    const float* __restrict__ x,
    const float* __restrict__ W0, const float* __restrict__ W1,
    const float* __restrict__ W2, const float* __restrict__ W3,
    const float* __restrict__ W4,
    const float* __restrict__ bv0, const float* __restrict__ bv1,
    const float* __restrict__ bv2, const float* __restrict__ bv3,
    const float* __restrict__ bv4,
    const float* __restrict__ Wcls, const float* __restrict__ bcls,
    __bf16* hb0, __bf16* hb1, float* cb0, float* cb1,
    unsigned* ctr, float* out)
{
  __shared__ __bf16 Bs[5 * NKS * 512];   // 122,880 B: chunk (ks*5+g) = 64 lanes x 16B

  const int tid = threadIdx.x;
  const int jt = (blockIdx.x >> 3) & 3;
  const int stripe = (blockIdx.x & 7) + ((blockIdx.x >> 5) << 3);   // 0..63

  // ---- pack this block's B slice into LDS (once per kernel) ----
  for (int e = tid; e < 5 * NKS * 64; e += 512) {
    int c = e >> 6, l = e & 63;
    int ks = c / 5, g = c % 5;
    const float* W = (g == 0) ? W0 : (g == 1) ? W1 : (g == 2) ? W2 : (g == 3) ? W3 : W4;
    const float* s = W + (size_t)(jt * 32 + (l & 31)) * GDIM + ks * 16 + (l >> 5) * 8;
    float4 v0 = *(const float4*)s;
    float4 v1 = *(const float4*)(s + 4);
    bf16x8 w;
    w[0] = (__bf16)v0.x; w[1] = (__bf16)v0.y; w[2] = (__bf16)v0.z; w[3] = (__bf16)v0.w;
    w[4] = (__bf16)v1.x; w[5] = (__bf16)v1.y; w[6] = (__bf16)v1.z; w[7] = (__bf16)v1.w;
    *(bf16x8*)(Bs + (size_t)e * 8) = w;
  }
  __syncthreads();

  const int wave = tid >> 6;
  const int l = tid & 63;
  const int l31 = l & 31;
  const int half8 = (l >> 5) * 8;
  const int rh = (l >> 5) * 4;
  const int j = jt * 32 + l31;
  const float g0b = bv0[j], g1b = bv1[j], g2b = bv2[j], g3b = bv3[j], g4b = bv4[j];

  unsigned target = 0;
  for (int d = TDEPTH - 1; d >= 0; --d) {
    const int n = 1 << d;
    const int leaf = (d == TDEPTH - 1) ? 1 : 0;
    const int nks = leaf ? 8 : NKS;
    const int p = (TDEPTH - 1) - d;
    __bf16* h_out = (p & 1) ? hb1 : hb0;
    float*  c_out = (p & 1) ? cb1 : cb0;
    const __bf16* h_prev = (p & 1) ? hb0 : hb1;
    const float*  c_prev = (p & 1) ? cb0 : cb1;
    const int M = BATCH << d;
    const int TM = (M + 511) >> 9;       // m-tiles of 512 rows
    const int n2 = 2 * n;

    for (int t = stripe; t < TM; t += 64) {
      const int mbase = t * 512 + wave * 64;
      if (mbase < M) {
        size_t xp[2], hp[2];
#pragma unroll
        for (int sub = 0; sub < 2; ++sub) {
          int m = mbase + sub * 32 + l31;
          int b = m >> d;
          int id = m & (n - 1);
          xp[sub] = ((size_t)b * NTOT + (n - 1) + id) * HDIM;
          hp[sub] = ((size_t)b * n2 + 2 * id) * HDIM;
        }
        auto loadX = [&](int ks, int sub) -> bf16x8 {
          const float* s = x + xp[sub] + ks * 16 + half8;
          float4 v0 = *(const float4*)s;
          float4 v1 = *(const float4*)(s + 4);
          bf16x8 w;
          w[0] = (__bf16)v0.x; w[1] = (__bf16)v0.y; w[2] = (__bf16)v0.z; w[3] = (__bf16)v0.w;
          w[4] = (__bf16)v1.x; w[5] = (__bf16)v1.y; w[6] = (__bf16)v1.z; w[7] = (__bf16)v1.w;
          return w;
        };
        auto loadH = [&](int ks, int sub) -> bf16x8 {
          return *(const bf16x8*)(h_prev + hp[sub] + (ks >= 16 ? HDIM : 0) + (ks & 7) * 16 + half8);
        };

        f32x16 acc[2][5];
#pragma unroll
        for (int sub = 0; sub < 2; ++sub)
#pragma unroll
          for (int g = 0; g < 5; ++g)
#pragma unroll
            for (int r = 0; r < 16; ++r) acc[sub][g][r] = 0.f;

        bf16x8 a0 = loadX(0, 0);
        bf16x8 a1 = loadX(0, 1);
        for (int ks = 0; ks < nks; ++ks) {
          int kn = (ks + 1 < nks) ? ks + 1 : ks;
          bf16x8 na0, na1;
          if (kn < 8) { na0 = loadX(kn, 0); na1 = loadX(kn, 1); }
          else        { na0 = loadH(kn, 0); na1 = loadH(kn, 1); }
#pragma unroll
          for (int g = 0; g < 5; ++g) {
            bf16x8 bb = *(const bf16x8*)(Bs + (size_t)(ks * 5 + g) * 512 + l * 8);
            acc[0][g] = __builtin_amdgcn_mfma_f32_32x32x16_bf16(a0, bb, acc[0][g], 0, 0, 0);
            acc[1][g] = __builtin_amdgcn_mfma_f32_32x32x16_bf16(a1, bb, acc[1][g], 0, 0, 0);
          }
          a0 = na0; a1 = na1;
        }

        // epilogue: D layout col(j)=lane&31, row=(r&3)+8*(r>>2)+4*(lane>>5)
#pragma unroll
        for (int sub = 0; sub < 2; ++sub) {
          const int mb = mbase + sub * 32 + rh;
#pragma unroll
          for (int r = 0; r < 16; ++r) {
            int m = mb + (r & 3) + 8 * (r >> 2);
            int b = m >> d;
            int id = m & (n - 1);
            float gi = sigmoid_f(acc[sub][0][r] + g0b);
            float gl = sigmoid_f(acc[sub][1][r] + g1b);
            float gr = sigmoid_f(acc[sub][2][r] + g2b);
            float go = sigmoid_f(acc[sub][3][r] + g3b);
            float gu = tanh_f(acc[sub][4][r] + g4b);
            float cv = gi * gu;
            if (!leaf) {
              size_t cb = ((size_t)b * n2 + 2 * id) * HDIM + j;
              cv += gl * c_prev[cb] + gr * c_prev[cb + HDIM];
            }
            size_t ob = ((size_t)b * n + id) * HDIM + j;
            c_out[ob] = cv;
            h_out[ob] = (__bf16)(go * tanh_f(cv));
          }
        }
      }
      // no barrier inside t-loop
    }
    target += NBLK;
    gbar(ctr, target);
  }

  // ---- classifier (root h is in hb1): block 0, one thread per batch row ----
  if (blockIdx.x == 0 && tid < BATCH) {
    const __bf16* hr = hb1 + (size_t)tid * HDIM;
    float s[NCLS];
#pragma unroll
    for (int c = 0; c < NCLS; ++c) s[c] = bcls[c];
    for (int k = 0; k < HDIM; ++k) {
      float hv = (float)hr[k];
#pragma unroll
      for (int c = 0; c < NCLS; ++c) s[c] += hv * Wcls[c * HDIM + k];
    }
#pragma unroll
    for (int c = 0; c < NCLS; ++c) out[tid * NCLS + c] = s[c];
  }
}

extern "C" void kernel_launch(void* const* d_in, const int* in_sizes, int n_in,
                              void* d_out, int out_size, void* d_ws, size_t ws_size,
                              hipStream_t stream) {
  const float* x  = (const float*)d_in[0];
  const float* W[5]  = {(const float*)d_in[1], (const float*)d_in[3], (const float*)d_in[5],
                        (const float*)d_in[7], (const float*)d_in[9]};
  const float* bv[5] = {(const float*)d_in[2], (const float*)d_in[4], (const float*)d_in[6],
                        (const float*)d_in[8], (const float*)d_in[10]};
  const float* Wcls = (const float*)d_in[11];
  const float* bcls = (const float*)d_in[12];

  uint8_t* ws = (uint8_t*)d_ws;
  __bf16* hb0 = (__bf16*)ws;                       // 33.6 MB (levels 9,7,5,..)
  __bf16* hb1 = (__bf16*)(ws + 33554432);          // 16.8 MB (levels 8,6,..,0)
  float*  cb0 = (float*)(ws + 50331648);           // 67 MB
  float*  cb1 = (float*)(ws + 117440512);          // 33.6 MB
  unsigned* ctr = (unsigned*)(ws + 150994944);     // 64 B barrier counter

  hipMemsetAsync((void*)ctr, 0, 64, stream);
  fused_kernel<<<NBLK, 512, 0, stream>>>(
      x, W[0], W[1], W[2], W[3], W[4],
      bv[0], bv[1], bv[2], bv[3], bv[4],
      Wcls, bcls, hb0, hb1, cb0, cb1, ctr, (float*)d_out);
}